// Round 3
// baseline (3142.971 us; speedup 1.0000x reference)
//
#include <hip/hip_runtime.h>
#include <math.h>

// Problem constants
#define V_  8185
#define E_  353
#define H_  191
#define FH_ 764
#define Z_  13
#define T_  25
#define START_ 19
#define VP_ 8192
#define NT_ 32   // VP_/256 column tiles for logits (round-0 proven)
#define HS_ 192  // padded h row stride in LDS (16B-aligned float4 reads)
#define NB_ 384  // encoder grid: 24 col-slices x 16 row-groups

__device__ __forceinline__ float sigf(float x) { return 1.0f / (1.0f + expf(-x)); }

// ---------------------------------------------------------------------------
// Manual grid barrier (generation-counting). Agent-scope atomics +
// __threadfence give cross-XCD visibility (L2 writeback on release,
// invalidate on acquire) — same lowering grid.sync() uses, but with no
// cooperative-launch API (round-2's cooperative launch hung under graph
// capture). Safe because grid (384 blocks) < residency capacity
// (>=3 blocks/CU at 42KB LDS x 256 CUs): every block is resident.
// ---------------------------------------------------------------------------
__device__ __forceinline__ void grid_barrier(unsigned* cnt, unsigned* gen) {
  __syncthreads();
  if (threadIdx.x == 0) {
    __threadfence();   // flush this block's h writes to device scope
    unsigned g = __hip_atomic_load(gen, __ATOMIC_RELAXED, __HIP_MEMORY_SCOPE_AGENT);
    unsigned a = __hip_atomic_fetch_add(cnt, 1u, __ATOMIC_ACQ_REL, __HIP_MEMORY_SCOPE_AGENT);
    if (a == NB_ - 1u) {
      __hip_atomic_store(cnt, 0u, __ATOMIC_RELAXED, __HIP_MEMORY_SCOPE_AGENT);
      __hip_atomic_store(gen, g + 1u, __ATOMIC_RELEASE, __HIP_MEMORY_SCOPE_AGENT);
    } else {
      while (__hip_atomic_load(gen, __ATOMIC_ACQUIRE, __HIP_MEMORY_SCOPE_AGENT) == g)
        __builtin_amdgcn_s_sleep(1);
    }
    __threadfence();   // order remote h reads after the acquire
  }
  __syncthreads();
}

// ---------------------------------------------------------------------------
// Pad out_w (191 x 8185) -> WP (191 x 8192), zero-filled tail.
// ---------------------------------------------------------------------------
__global__ __launch_bounds__(256) void pad_w_kernel(const float* __restrict__ src,
                                                    float* __restrict__ dst) {
  int i = blockIdx.x * 256 + threadIdx.x;
  if (i >= H_ * VP_) return;
  int k = i >> 13;            // row (VP_=8192=2^13)
  int j = i & (VP_ - 1);      // col
  dst[i] = (j < V_) ? src[(size_t)k * V_ + j] : 0.0f;
}

// ---------------------------------------------------------------------------
// C[M][764] = A_rows[M][353] @ W[353][764]   (round-0 proven version)
// mode 0: A row m = emb[m]                      (EK = emb @ gen_k, M=V)
// mode 1: A row m=(t*B+b) = emb[inputs[b*T+t]]  (XK, M=T*B)
// ---------------------------------------------------------------------------
__global__ __launch_bounds__(256) void gemm_ew(const float* __restrict__ emb,
                                               const float* __restrict__ W,
                                               float* __restrict__ C, int M,
                                               const int* __restrict__ inputs,
                                               int mode, int B) {
  __shared__ __align__(16) float AT[E_ * 16];
  const int tid = threadIdx.x;
  const int n0 = blockIdx.x * 256;
  const int m0 = blockIdx.y * 16;
  for (int i = tid; i < 16 * E_; i += 256) {
    int r = i / E_, k = i - r * E_;
    int m = m0 + r;
    float v = 0.0f;
    if (m < M) {
      int row;
      if (mode == 0) row = m;
      else { int t = m / B, b = m - t * B; row = inputs[b * T_ + t]; }
      v = emb[(size_t)row * E_ + k];
    }
    AT[k * 16 + r] = v;
  }
  __syncthreads();
  const int lane = tid & 63;
  const int w4 = (tid >> 6) * 4;
  const int j = n0 + lane * 4;
  if (j >= FH_) return;  // 764 % 4 == 0: lanes are fully valid or fully out
  float4 c0 = {0,0,0,0}, c1 = {0,0,0,0}, c2 = {0,0,0,0}, c3 = {0,0,0,0};
  const float* wc = W + j;
  const float* at = AT + w4;
  for (int k = 0; k < E_; ++k) {
    float4 wv = *(const float4*)(wc + (size_t)k * FH_);
    float4 a  = *(const float4*)(at + k * 16);
    c0.x = fmaf(a.x, wv.x, c0.x); c0.y = fmaf(a.x, wv.y, c0.y);
    c0.z = fmaf(a.x, wv.z, c0.z); c0.w = fmaf(a.x, wv.w, c0.w);
    c1.x = fmaf(a.y, wv.x, c1.x); c1.y = fmaf(a.y, wv.y, c1.y);
    c1.z = fmaf(a.y, wv.z, c1.z); c1.w = fmaf(a.y, wv.w, c1.w);
    c2.x = fmaf(a.z, wv.x, c2.x); c2.y = fmaf(a.z, wv.y, c2.y);
    c2.z = fmaf(a.z, wv.z, c2.z); c2.w = fmaf(a.z, wv.w, c2.w);
    c3.x = fmaf(a.w, wv.x, c3.x); c3.y = fmaf(a.w, wv.y, c3.y);
    c3.z = fmaf(a.w, wv.z, c3.z); c3.w = fmaf(a.w, wv.w, c3.w);
  }
  const int mb = m0 + w4;
  if (mb + 0 < M) *(float4*)(C + (size_t)(mb + 0) * FH_ + j) = c0;
  if (mb + 1 < M) *(float4*)(C + (size_t)(mb + 1) * FH_ + j) = c1;
  if (mb + 2 < M) *(float4*)(C + (size_t)(mb + 2) * FH_ + j) = c2;
  if (mb + 3 < M) *(float4*)(C + (size_t)(mb + 3) * FH_ + j) = c3;
}

// ---------------------------------------------------------------------------
// Persistent encoder + latent + decoder init, ONE dispatch.
// Grid (24 col-slices, 16 row-groups) = 384 blocks x 256 threads.
// Block (cb, rg): owns h-cols [cb*8, cb*8+8) x 16 batch rows.
//  - rk slice (32 gate cols x 191) staged in LDS ONCE (24.4 KB) — round-1's
//    390 µs encoder was exactly this slice re-read from L2, latency-bound
//  - c state lives in pointwise threads' registers across all 25 steps
//  - h exchanged via double-buffered global array + manual grid barrier
// All accumulation chains keep round-0 k-ordering -> bitwise-identical output.
// ---------------------------------------------------------------------------
__global__ __launch_bounds__(256) void encoder_persist(
    const float* __restrict__ xk,    // XK: (T*B, 764), row (t*B + b)
    const float* __restrict__ rk,    // inf_rk (191, 764)
    const float* __restrict__ bias,  // inf_b (764)
    const float* __restrict__ eps,
    const float* __restrict__ mu_w, const float* __restrict__ mu_b,
    const float* __restrict__ sig_w, const float* __restrict__ sig_b,
    const float* __restrict__ iw, const float* __restrict__ ib,
    float* __restrict__ h0o, float* __restrict__ c0o,
    float* __restrict__ hb0, float* __restrict__ hb1,
    unsigned* __restrict__ bar, int B) {
  __shared__ float rks[H_ * 32];                 // [k][q] — conflict-free reads
  __shared__ __align__(16) float hs[16 * HS_];   // staged h rows (padded)
  __shared__ float xs[16 * 32];
  __shared__ float bs[32];
  __shared__ float gb[32 * 16];
  __shared__ float zz[16 * Z_];

  const int tid = threadIdx.x;
  const int c0 = blockIdx.x * 8;
  const int m0 = blockIdx.y * 16;

  // one-time: stage rk slice + bias
  for (int i = tid; i < H_ * 32; i += 256) {
    int k = i >> 5, qq = i & 31;
    int j2 = c0 + (qq & 7);
    rks[i] = (j2 < H_) ? rk[(size_t)k * FH_ + j2 + H_ * (qq >> 3)] : 0.0f;
  }
  if (tid < 32) {
    int j2 = c0 + (tid & 7);
    bs[tid] = (j2 < H_) ? bias[j2 + H_ * (tid >> 3)] : 0.0f;
  }

  const int q = tid & 31, r2 = tid >> 5;   // dot role: col-slot q, rows r2/r2+8
  const int jj = c0 + (q & 7);
  const int pc = tid & 7, prow = tid >> 3; // pointwise role (tid<128)
  float creg = 0.0f;                       // c state, never leaves registers

  float* hbuf[2] = {hb0, hb1};
  __syncthreads();

  for (int t = 0; t < T_; ++t) {
    // stage h (t>0; t==0 has h=0 so the dot is skipped) and x-gate values
    if (t > 0) {
      const float* hsrc = hbuf[t & 1] + (size_t)m0 * H_;
      for (int i = tid; i < 16 * H_; i += 256) {
        int r = i / H_, k = i - r * H_;
        hs[r * HS_ + k] = hsrc[i];
      }
    }
    for (int i = tid; i < 16 * 32; i += 256) {
      int row = i >> 5, qq = i & 31;
      int j2 = c0 + (qq & 7);
      float xv = 0.0f;
      if (j2 < H_)
        xv = xk[((size_t)t * B + m0 + row) * FH_ + j2 + H_ * (qq >> 3)];
      xs[i] = xv;
    }
    __syncthreads();

    // recurrent dot (k ascending single chain -> bitwise == round-0)
    float a0 = 0.0f, a1 = 0.0f;
    if (t > 0 && jj < H_) {
      const float* h0p = hs + r2 * HS_;
      const float* h1p = hs + (r2 + 8) * HS_;
      int k = 0;
      for (; k < 188; k += 4) {
        float4 h0v = *(const float4*)(h0p + k);   // half-wave broadcast
        float4 h1v = *(const float4*)(h1p + k);
        float w0 = rks[(k + 0) * 32 + q], w1 = rks[(k + 1) * 32 + q];
        float w2 = rks[(k + 2) * 32 + q], w3 = rks[(k + 3) * 32 + q];
        a0 = fmaf(h0v.x, w0, a0); a1 = fmaf(h1v.x, w0, a1);
        a0 = fmaf(h0v.y, w1, a0); a1 = fmaf(h1v.y, w1, a1);
        a0 = fmaf(h0v.z, w2, a0); a1 = fmaf(h1v.z, w2, a1);
        a0 = fmaf(h0v.w, w3, a0); a1 = fmaf(h1v.w, w3, a1);
      }
      for (; k < H_; ++k) {
        float wv = rks[k * 32 + q];
        a0 = fmaf(h0p[k], wv, a0);
        a1 = fmaf(h1p[k], wv, a1);
      }
    }
    gb[q * 16 + r2] = a0;
    gb[q * 16 + r2 + 8] = a1;
    __syncthreads();

    // pointwise LSTM update; write h to the other global buffer
    if (tid < 128) {
      int jc = c0 + pc;
      if (jc < H_) {
        float gi = gb[(pc     ) * 16 + prow] + xs[prow * 32 + pc     ] + bs[pc];
        float gf = gb[( 8 + pc) * 16 + prow] + xs[prow * 32 +  8 + pc] + bs[ 8 + pc];
        float gg = gb[(16 + pc) * 16 + prow] + xs[prow * 32 + 16 + pc] + bs[16 + pc];
        float go = gb[(24 + pc) * 16 + prow] + xs[prow * 32 + 24 + pc] + bs[24 + pc];
        float cn = sigf(gf) * creg + sigf(gi) * tanhf(gg);
        creg = cn;
        hbuf[(t + 1) & 1][(size_t)(m0 + prow) * H_ + jc] = sigf(go) * tanhf(cn);
      }
    }
    grid_barrier(bar, bar + 1);
  }

  // latent + decoder-init for this row-group (only col-slice 0 blocks)
  if (blockIdx.x == 0) {
    const float* hf = hbuf[T_ & 1] + (size_t)m0 * H_;
    for (int i = tid; i < 16 * H_; i += 256) {
      int r = i / H_, k = i - r * H_;
      hs[r * HS_ + k] = hf[i];
    }
    __syncthreads();
    if (tid < 16 * Z_) {
      int row = tid / Z_, zq = tid - row * Z_;
      const float* hr = hs + row * HS_;
      float mu = mu_b[zq], sg = sig_b[zq];
      for (int k = 0; k < H_; ++k) {
        float hv = hr[k];
        mu = fmaf(hv, mu_w[k * Z_ + zq], mu);
        sg = fmaf(hv, sig_w[k * Z_ + zq], sg);
      }
      zz[tid] = mu + eps[zq] * sg;
    }
    __syncthreads();
    for (int i = tid; i < 16 * H_; i += 256) {
      int row = i / H_, col = i - row * H_;
      float acc = ib[col];
#pragma unroll
      for (int z = 0; z < Z_; ++z)
        acc = fmaf(zz[row * Z_ + z], iw[z * H_ + col], acc);
      h0o[(size_t)(m0 + row) * H_ + col] = acc;
      c0o[(size_t)(m0 + row) * H_ + col] = acc;
    }
  }
}

// ---------------------------------------------------------------------------
// Decoder LSTM step (round-0 proven). Block owns h-cols [c0,c0+8) x 16 rows.
// ---------------------------------------------------------------------------
__global__ __launch_bounds__(256) void lstm_step(const float* __restrict__ xk,
                                                 const float* __restrict__ rk,
                                                 const float* __restrict__ bias,
                                                 const float* __restrict__ h_in,
                                                 const float* __restrict__ c_in,
                                                 float* __restrict__ h_out,
                                                 float* __restrict__ c_out,
                                                 const float* __restrict__ pmax,
                                                 const int* __restrict__ pidx,
                                                 int mode, int first) {
  __shared__ float hs[16 * H_];
  __shared__ float xs[16 * 32];
  __shared__ float bs[32];
  __shared__ int   tk[16];
  __shared__ float pv[16 * NT_];
  __shared__ int   pi[16 * NT_];
  __shared__ float gb[32 * 16];

  const int tid = threadIdx.x;
  const int c0 = blockIdx.x * 8;
  const int m0 = blockIdx.y * 16;

  if (mode) {
    if (first) {
      if (tid < 16) tk[tid] = START_;
    } else {
      for (int i = tid; i < 16 * NT_; i += 256) {
        int row = i >> 5, s = i & (NT_ - 1);
        pv[i] = pmax[(size_t)(m0 + row) * NT_ + s];
        pi[i] = pidx[(size_t)(m0 + row) * NT_ + s];
      }
      __syncthreads();
      if (tid < 16) {
        float bv = pv[tid * NT_]; int bi = pi[tid * NT_];
        for (int s = 1; s < NT_; ++s) {
          float v = pv[tid * NT_ + s]; int ii = pi[tid * NT_ + s];
          if (v > bv || (v == bv && ii < bi)) { bv = v; bi = ii; }
        }
        tk[tid] = bi;
      }
    }
    __syncthreads();
  }

  // stage h rows (contiguous copy)
  for (int i = tid; i < 16 * H_; i += 256) hs[i] = h_in[(size_t)m0 * H_ + i];
  // stage x gate values and bias for this block's 32 gate columns
  for (int i = tid; i < 16 * 32; i += 256) {
    int row = i >> 5, q = i & 31;
    int jj = c0 + (q & 7);
    int jg = jj + H_ * (q >> 3);
    float xv = 0.0f;
    if (jj < H_) {
      const float* xrow = mode ? (xk + (size_t)tk[row] * FH_)
                               : (xk + (size_t)(m0 + row) * FH_);
      xv = xrow[jg];
    }
    xs[i] = xv;
  }
  if (tid < 32) {
    int jj = c0 + (tid & 7);
    bs[tid] = (jj < H_) ? bias[jj + H_ * (tid >> 3)] : 0.0f;
  }
  __syncthreads();

  // recurrent dot: thread = (gate-col slot q, row-group rg); 2 rows each
  const int q = tid & 31, rg = tid >> 5;
  const int jj = c0 + (q & 7);
  const int jg = jj + H_ * (q >> 3);
  float a0 = 0.0f, a1 = 0.0f;
  if (jj < H_) {
    const float* rkp = rk + jg;
    const float* h0p = hs + rg * H_;
    const float* h1p = hs + (rg + 8) * H_;
    for (int k = 0; k < H_; ++k) {
      float wv = rkp[(size_t)k * FH_];
      a0 = fmaf(h0p[k], wv, a0);
      a1 = fmaf(h1p[k], wv, a1);
    }
  }
  gb[q * 16 + rg] = a0;
  gb[q * 16 + rg + 8] = a1;
  __syncthreads();

  // pointwise LSTM update for (8 cols x 16 rows)
  if (tid < 128) {
    int cc = tid & 7, row = tid >> 3;
    int jc = c0 + cc;
    if (jc < H_) {
      float gi = gb[(cc      ) * 16 + row] + xs[row * 32 + cc      ] + bs[cc];
      float gf = gb[( 8 + cc ) * 16 + row] + xs[row * 32 +  8 + cc ] + bs[ 8 + cc];
      float gg = gb[(16 + cc ) * 16 + row] + xs[row * 32 + 16 + cc ] + bs[16 + cc];
      float go = gb[(24 + cc ) * 16 + row] + xs[row * 32 + 24 + cc ] + bs[24 + cc];
      float co = c_in[(size_t)(m0 + row) * H_ + jc];
      float cn = sigf(gf) * co + sigf(gi) * tanhf(gg);
      float hn = sigf(go) * tanhf(cn);
      c_out[(size_t)(m0 + row) * H_ + jc] = cn;
      h_out[(size_t)(m0 + row) * H_ + jc] = hn;
    }
  }
}

// ---------------------------------------------------------------------------
// logits = h @ WP + out_b ; write to out[:, t, :]; per-(row, col-tile)
// argmax partials. Round-0 proven: 16 rows x 256 cols, grid (32, B/16).
// ---------------------------------------------------------------------------
__global__ __launch_bounds__(256) void logits_argmax(const float* __restrict__ h,
                                                     const float* __restrict__ wp,
                                                     const float* __restrict__ ob,
                                                     float* __restrict__ out, int t,
                                                     float* __restrict__ pmax,
                                                     int* __restrict__ pidx) {
  __shared__ __align__(16) float AT[H_ * 16];
  const int tid = threadIdx.x;
  const int n0 = blockIdx.x * 256;
  const int m0 = blockIdx.y * 16;
  for (int i = tid; i < 16 * H_; i += 256) {
    int r = i / H_, k = i - r * H_;
    AT[k * 16 + r] = h[(size_t)m0 * H_ + i];
  }
  __syncthreads();
  const int lane = tid & 63;
  const int w4 = (tid >> 6) * 4;
  const int j = n0 + lane * 4;
  float4 c0 = {0,0,0,0}, c1 = {0,0,0,0}, c2 = {0,0,0,0}, c3 = {0,0,0,0};
  const float* wc = wp + j;
  const float* at = AT + w4;
  for (int k = 0; k < H_; ++k) {
    float4 wv = *(const float4*)(wc + (size_t)k * VP_);
    float4 a  = *(const float4*)(at + k * 16);
    c0.x = fmaf(a.x, wv.x, c0.x); c0.y = fmaf(a.x, wv.y, c0.y);
    c0.z = fmaf(a.x, wv.z, c0.z); c0.w = fmaf(a.x, wv.w, c0.w);
    c1.x = fmaf(a.y, wv.x, c1.x); c1.y = fmaf(a.y, wv.y, c1.y);
    c1.z = fmaf(a.y, wv.z, c1.z); c1.w = fmaf(a.y, wv.w, c1.w);
    c2.x = fmaf(a.z, wv.x, c2.x); c2.y = fmaf(a.z, wv.y, c2.y);
    c2.z = fmaf(a.z, wv.z, c2.z); c2.w = fmaf(a.z, wv.w, c2.w);
    c3.x = fmaf(a.w, wv.x, c3.x); c3.y = fmaf(a.w, wv.y, c3.y);
    c3.z = fmaf(a.w, wv.z, c3.z); c3.w = fmaf(a.w, wv.w, c3.w);
  }
  float bias[4];
#pragma unroll
  for (int u = 0; u < 4; ++u) bias[u] = (j + u < V_) ? ob[j + u] : 0.0f;
  float4 accs[4] = {c0, c1, c2, c3};
  const int b0 = m0 + w4;
#pragma unroll
  for (int r = 0; r < 4; ++r) {
    const int b = b0 + r;
    float v[4] = {accs[r].x + bias[0], accs[r].y + bias[1],
                  accs[r].z + bias[2], accs[r].w + bias[3]};
    float* orow = out + ((size_t)b * T_ + t) * V_ + j;
#pragma unroll
    for (int u = 0; u < 4; ++u)
      if (j + u < V_) orow[u] = v[u];
    float bv = -INFINITY; int bi = 0;
#pragma unroll
    for (int u = 0; u < 4; ++u)
      if (j + u < V_ && v[u] > bv) { bv = v[u]; bi = j + u; }
#pragma unroll
    for (int off = 1; off < 64; off <<= 1) {
      float ov = __shfl_xor(bv, off, 64);
      int   oi = __shfl_xor(bi, off, 64);
      if (ov > bv || (ov == bv && oi < bi)) { bv = ov; bi = oi; }
    }
    if (lane == 0) {
      pmax[(size_t)b * NT_ + blockIdx.x] = bv;
      pidx[(size_t)b * NT_ + blockIdx.x] = bi;
    }
  }
}

// ---------------------------------------------------------------------------
extern "C" void kernel_launch(void* const* d_in, const int* in_sizes, int n_in,
                              void* d_out, int out_size, void* d_ws, size_t ws_size,
                              hipStream_t stream) {
  const int*   inputs = (const int*)  d_in[0];
  const float* eps    = (const float*)d_in[1];
  const float* emb    = (const float*)d_in[2];
  const float* inf_k  = (const float*)d_in[3];
  const float* inf_rk = (const float*)d_in[4];
  const float* inf_b  = (const float*)d_in[5];
  const float* mu_w   = (const float*)d_in[6];
  const float* mu_b   = (const float*)d_in[7];
  const float* sig_w  = (const float*)d_in[8];
  const float* sig_b  = (const float*)d_in[9];
  const float* init_w = (const float*)d_in[10];
  const float* init_b = (const float*)d_in[11];
  const float* gen_k  = (const float*)d_in[12];
  const float* gen_rk = (const float*)d_in[13];
  const float* gen_b  = (const float*)d_in[14];
  const float* out_w  = (const float*)d_in[15];
  const float* out_b  = (const float*)d_in[16];
  float* out = (float*)d_out;

  const int B = in_sizes[0] / T_;        // 256
  const int BH = B * H_;

  float* ws = (float*)d_ws;
  size_t off = 0;
  float* EK = ws + off; off += (size_t)V_ * FH_;        // emb @ gen_k
  float* XK = ws + off; off += (size_t)T_ * B * FH_;    // gathered emb @ inf_k
  float* WP = ws + off; off += (size_t)H_ * VP_;        // padded out_w
  float* hbase = ws + off; off += (size_t)4 * BH;       // hd0 cd0 hd1 cd1
  float* hd[2] = {hbase + 0 * BH, hbase + 2 * BH};
  float* cd[2] = {hbase + 1 * BH, hbase + 3 * BH};
  float* hb0 = ws + off; off += (size_t)BH;             // encoder h exchange
  float* hb1 = ws + off; off += (size_t)BH;
  float* pmax = ws + off; off += (size_t)B * NT_;
  int*   pidx = (int*)(ws + off); off += (size_t)B * NT_;
  unsigned* bar = (unsigned*)(ws + off); off += 2;      // {count, generation}

  // reset barrier state (graph replays this each iteration)
  hipMemsetAsync(bar, 0, 2 * sizeof(unsigned), stream);

  // one-time parallel precomputes (round-0 proven)
  pad_w_kernel<<<(H_ * VP_ + 255) / 256, 256, 0, stream>>>(out_w, WP);
  gemm_ew<<<dim3(3, (V_ + 15) / 16), 256, 0, stream>>>(emb, gen_k, EK, V_, nullptr, 0, B);
  gemm_ew<<<dim3(3, (T_ * B) / 16), 256, 0, stream>>>(emb, inf_k, XK, T_ * B, inputs, 1, B);

  // persistent encoder (+ latent + decoder init), one dispatch, manual barrier
  encoder_persist<<<dim3(24, B / 16), 256, 0, stream>>>(
      XK, inf_rk, inf_b, eps, mu_w, mu_b, sig_w, sig_b,
      init_w, init_b, hd[0], cd[0], hb0, hb1, bar, B);

  // autoregressive decoder (round-0 proven)
  for (int t = 0; t < T_; ++t) {
    lstm_step<<<dim3(24, B / 16), 256, 0, stream>>>(
        EK, gen_rk, gen_b,
        hd[t & 1], cd[t & 1], hd[(t + 1) & 1], cd[(t + 1) & 1],
        pmax, pidx, 1, (t == 0) ? 1 : 0);
    logits_argmax<<<dim3(NT_, B / 16), 256, 0, stream>>>(
        hd[(t + 1) & 1], WP, out_b, out, t, pmax, pidx);
  }
}

// Round 4
// 1723.742 us; speedup vs baseline: 1.8233x; 1.8233x over previous
//
#include <hip/hip_runtime.h>
#include <math.h>

// Problem constants
#define V_  8185
#define E_  353
#define H_  191
#define FH_ 764
#define Z_  13
#define T_  25
#define START_ 19
#define VP_ 8192
#define NTL 64      // logits col-tiles (128 cols each)
#define RKS 192     // padded k-stride of transposed rk (16B-aligned float4)

__device__ __forceinline__ float sigf(float x) { return 1.0f / (1.0f + expf(-x)); }

// ---------------------------------------------------------------------------
// Pad out_w (191 x 8185) -> WP (191 x 8192), zero-filled tail.
// ---------------------------------------------------------------------------
__global__ __launch_bounds__(256) void pad_w_kernel(const float* __restrict__ src,
                                                    float* __restrict__ dst) {
  int i = blockIdx.x * 256 + threadIdx.x;
  if (i >= H_ * VP_) return;
  int k = i >> 13;            // row (VP_=8192=2^13)
  int j = i & (VP_ - 1);      // col
  dst[i] = (j < V_) ? src[(size_t)k * V_ + j] : 0.0f;
}

// ---------------------------------------------------------------------------
// Transpose inf_rk and gen_rk (191 x 764) -> rkT[2][764][192], zero pad k=191.
// Lets lstm_step stage its rk slice with coalesced float4 loads instead of
// 191 scalar 3KB-strided L2 reads per thread (the round-0 latency bottleneck).
// ---------------------------------------------------------------------------
__global__ __launch_bounds__(256) void transpose_rk(const float* __restrict__ rkA,
                                                    const float* __restrict__ rkB,
                                                    float* __restrict__ dst) {
  int i = blockIdx.x * 256 + threadIdx.x;
  if (i >= 2 * FH_ * RKS) return;
  int w = i / (FH_ * RKS), rem = i - w * (FH_ * RKS);
  int col4 = rem / RKS, k = rem - col4 * RKS;
  const float* src = w ? rkB : rkA;
  dst[i] = (k < H_) ? src[(size_t)k * FH_ + col4] : 0.0f;
}

// ---------------------------------------------------------------------------
// C[M][764] = A_rows[M][353] @ W[353][764]   (round-0 proven version)
// mode 0: A row m = emb[m]                      (EK = emb @ gen_k, M=V)
// mode 1: A row m=(t*B+b) = emb[inputs[b*T+t]]  (XK, M=T*B)
// ---------------------------------------------------------------------------
__global__ __launch_bounds__(256) void gemm_ew(const float* __restrict__ emb,
                                               const float* __restrict__ W,
                                               float* __restrict__ C, int M,
                                               const int* __restrict__ inputs,
                                               int mode, int B) {
  __shared__ __align__(16) float AT[E_ * 16];
  const int tid = threadIdx.x;
  const int n0 = blockIdx.x * 256;
  const int m0 = blockIdx.y * 16;
  for (int i = tid; i < 16 * E_; i += 256) {
    int r = i / E_, k = i - r * E_;
    int m = m0 + r;
    float v = 0.0f;
    if (m < M) {
      int row;
      if (mode == 0) row = m;
      else { int t = m / B, b = m - t * B; row = inputs[b * T_ + t]; }
      v = emb[(size_t)row * E_ + k];
    }
    AT[k * 16 + r] = v;
  }
  __syncthreads();
  const int lane = tid & 63;
  const int w4 = (tid >> 6) * 4;
  const int j = n0 + lane * 4;
  if (j >= FH_) return;  // 764 % 4 == 0: lanes are fully valid or fully out
  float4 c0 = {0,0,0,0}, c1 = {0,0,0,0}, c2 = {0,0,0,0}, c3 = {0,0,0,0};
  const float* wc = W + j;
  const float* at = AT + w4;
  for (int k = 0; k < E_; ++k) {
    float4 wv = *(const float4*)(wc + (size_t)k * FH_);
    float4 a  = *(const float4*)(at + k * 16);
    c0.x = fmaf(a.x, wv.x, c0.x); c0.y = fmaf(a.x, wv.y, c0.y);
    c0.z = fmaf(a.x, wv.z, c0.z); c0.w = fmaf(a.x, wv.w, c0.w);
    c1.x = fmaf(a.y, wv.x, c1.x); c1.y = fmaf(a.y, wv.y, c1.y);
    c1.z = fmaf(a.y, wv.z, c1.z); c1.w = fmaf(a.y, wv.w, c1.w);
    c2.x = fmaf(a.z, wv.x, c2.x); c2.y = fmaf(a.z, wv.y, c2.y);
    c2.z = fmaf(a.z, wv.z, c2.z); c2.w = fmaf(a.z, wv.w, c2.w);
    c3.x = fmaf(a.w, wv.x, c3.x); c3.y = fmaf(a.w, wv.y, c3.y);
    c3.z = fmaf(a.w, wv.z, c3.z); c3.w = fmaf(a.w, wv.w, c3.w);
  }
  const int mb = m0 + w4;
  if (mb + 0 < M) *(float4*)(C + (size_t)(mb + 0) * FH_ + j) = c0;
  if (mb + 1 < M) *(float4*)(C + (size_t)(mb + 1) * FH_ + j) = c1;
  if (mb + 2 < M) *(float4*)(C + (size_t)(mb + 2) * FH_ + j) = c2;
  if (mb + 3 < M) *(float4*)(C + (size_t)(mb + 3) * FH_ + j) = c3;
}

// ---------------------------------------------------------------------------
// One LSTM step (round-0 structure, rk path rebuilt):
//  - rk slice now staged into LDS via COALESCED float4 loads from rkT
//    (round-0 read rk[k*764] per thread: 191 scalar strided L2 loads,
//     latency-bound at 1.5 blocks/CU)
//  - dot reads rks[q][k] (pad 193 -> conflict-free) + float4-broadcast h
//  - k-ascending single fma chain per output -> bitwise == round-0
// Block owns h-cols [c0,c0+8) x 16 batch rows; grid (24, B/16).
// mode 0 (encoder): xrow = xk + (m0+row)*764;  mode 1 (decoder): EK[token].
// ---------------------------------------------------------------------------
__global__ __launch_bounds__(256) void lstm_step(const float* __restrict__ xk,
                                                 const float* __restrict__ rkT,
                                                 const float* __restrict__ bias,
                                                 const float* __restrict__ h_in,
                                                 const float* __restrict__ c_in,
                                                 float* __restrict__ h_out,
                                                 float* __restrict__ c_out,
                                                 const float* __restrict__ pmax,
                                                 const int* __restrict__ pidx,
                                                 int mode, int first) {
  __shared__ float rks[32][193];                  // 24.7 KB, conflict-free
  __shared__ __align__(16) float hs[16][RKS];     // 12.3 KB, float4-readable
  __shared__ float xs[16 * 32];
  __shared__ float bs[32];
  __shared__ int   tk[16];
  __shared__ float pv[16 * NTL];
  __shared__ int   pi[16 * NTL];
  __shared__ float gb[32 * 16];

  const int tid = threadIdx.x;
  const int c0 = blockIdx.x * 8;
  const int m0 = blockIdx.y * 16;

  if (mode) {
    if (first) {
      if (tid < 16) tk[tid] = START_;
    } else {
      for (int i = tid; i < 16 * NTL; i += 256) {
        int row = i >> 6, s = i & (NTL - 1);
        pv[i] = pmax[(size_t)(m0 + row) * NTL + s];
        pi[i] = pidx[(size_t)(m0 + row) * NTL + s];
      }
      __syncthreads();
      if (tid < 16) {
        float bv = pv[tid * NTL]; int bi = pi[tid * NTL];
        for (int s = 1; s < NTL; ++s) {
          float v = pv[tid * NTL + s]; int ii = pi[tid * NTL + s];
          if (v > bv || (v == bv && ii < bi)) { bv = v; bi = ii; }
        }
        tk[tid] = bi;
      }
    }
    __syncthreads();
  }

  // stage rk slice (32 gate cols x 192 k) from rkT — fully coalesced float4
  for (int i = tid; i < 32 * 48; i += 256) {
    int qq = i / 48, kq = (i - qq * 48) * 4;
    int jj2 = c0 + (qq & 7), g = qq >> 3;
    float4 v = {0, 0, 0, 0};
    if (jj2 < H_) v = *(const float4*)(rkT + (size_t)(jj2 + H_ * g) * RKS + kq);
    rks[qq][kq]     = v.x; rks[qq][kq + 1] = v.y;
    rks[qq][kq + 2] = v.z; rks[qq][kq + 3] = v.w;
  }
  // stage h rows (coalesced read, padded rows for aligned float4 re-read)
  for (int i = tid; i < 16 * H_; i += 256) {
    int r = i / H_, k = i - r * H_;
    hs[r][k] = h_in[(size_t)m0 * H_ + i];
  }
  // stage x gate values and bias for this block's 32 gate columns
  for (int i = tid; i < 16 * 32; i += 256) {
    int row = i >> 5, q = i & 31;
    int jj = c0 + (q & 7);
    int jg = jj + H_ * (q >> 3);
    float xv = 0.0f;
    if (jj < H_) {
      const float* xrow = mode ? (xk + (size_t)tk[row] * FH_)
                               : (xk + (size_t)(m0 + row) * FH_);
      xv = xrow[jg];
    }
    xs[i] = xv;
  }
  if (tid < 32) {
    int jj = c0 + (tid & 7);
    bs[tid] = (jj < H_) ? bias[jj + H_ * (tid >> 3)] : 0.0f;
  }
  __syncthreads();

  // recurrent dot: thread = (gate-col slot q, row-group rg); 2 rows each.
  // rks read: banks (q*193+k)%32 = (q+k)%32 distinct per q -> conflict-free.
  // hs read: half-wave uniform address -> broadcast.
  const int q = tid & 31, rg = tid >> 5;
  const int jj = c0 + (q & 7);
  float a0 = 0.0f, a1 = 0.0f;
  if (jj < H_) {
    const float* rr  = rks[q];
    const float* h0p = hs[rg];
    const float* h1p = hs[rg + 8];
    int k = 0;
    for (; k < 188; k += 4) {
      float4 h0v = *(const float4*)(h0p + k);
      float4 h1v = *(const float4*)(h1p + k);
      float w0 = rr[k], w1 = rr[k + 1], w2 = rr[k + 2], w3 = rr[k + 3];
      a0 = fmaf(h0v.x, w0, a0); a1 = fmaf(h1v.x, w0, a1);
      a0 = fmaf(h0v.y, w1, a0); a1 = fmaf(h1v.y, w1, a1);
      a0 = fmaf(h0v.z, w2, a0); a1 = fmaf(h1v.z, w2, a1);
      a0 = fmaf(h0v.w, w3, a0); a1 = fmaf(h1v.w, w3, a1);
    }
    for (; k < H_; ++k) {
      float wv = rr[k];
      a0 = fmaf(h0p[k], wv, a0);
      a1 = fmaf(h1p[k], wv, a1);
    }
  }
  gb[q * 16 + rg] = a0;
  gb[q * 16 + rg + 8] = a1;
  __syncthreads();

  // pointwise LSTM update for (8 cols x 16 rows)
  if (tid < 128) {
    int cc = tid & 7, row = tid >> 3;
    int jc = c0 + cc;
    if (jc < H_) {
      float gi = gb[(cc      ) * 16 + row] + xs[row * 32 + cc      ] + bs[cc];
      float gf = gb[( 8 + cc ) * 16 + row] + xs[row * 32 +  8 + cc ] + bs[ 8 + cc];
      float gg = gb[(16 + cc ) * 16 + row] + xs[row * 32 + 16 + cc ] + bs[16 + cc];
      float go = gb[(24 + cc ) * 16 + row] + xs[row * 32 + 24 + cc ] + bs[24 + cc];
      float co = c_in[(size_t)(m0 + row) * H_ + jc];
      float cn = sigf(gf) * co + sigf(gi) * tanhf(gg);
      float hn = sigf(go) * tanhf(cn);
      c_out[(size_t)(m0 + row) * H_ + jc] = cn;
      h_out[(size_t)(m0 + row) * H_ + jc] = hn;
    }
  }
}

// ---------------------------------------------------------------------------
// logits = h @ WP + out_b ; out[:, t, :]; per-(row, col-tile) argmax partials.
// Tile 32 rows x 128 cols (round-0 was 16x256): WP re-read 8x/step not 16x.
// 256 threads: thread (cq=tid&31, ro=tid>>5) = cols [n0+cq*4,+4) x rows
// [m0+ro*4,+4). Same float4 WP loads + broadcast AT reads as round-0;
// per-output k-chain unchanged -> bitwise-identical logits.
// Grid (NTL=64, B/32) = 512 blocks, 2/CU (same as round-0).
// ---------------------------------------------------------------------------
__global__ __launch_bounds__(256) void logits_argmax(const float* __restrict__ h,
                                                     const float* __restrict__ wp,
                                                     const float* __restrict__ ob,
                                                     float* __restrict__ out, int t,
                                                     float* __restrict__ pmax,
                                                     int* __restrict__ pidx) {
  __shared__ __align__(16) float AT[H_ * 36];   // [k][36-pad r]: aligned float4
  const int tid = threadIdx.x;
  const int n0 = blockIdx.x * 128;
  const int m0 = blockIdx.y * 32;
  for (int i = tid; i < 32 * H_; i += 256) {
    int r = i / H_, k = i - r * H_;
    AT[k * 36 + r] = h[(size_t)m0 * H_ + i];
  }
  __syncthreads();

  const int cq = tid & 31;   // col quad within tile
  const int ro = tid >> 5;   // row octet (4 rows each)
  const int j = n0 + cq * 4;
  float4 acc[4] = {{0,0,0,0},{0,0,0,0},{0,0,0,0},{0,0,0,0}};
  const float* wc = wp + j;
  const float* at = AT + ro * 4;
  for (int k = 0; k < H_; ++k) {
    float4 wv = *(const float4*)(wc + (size_t)k * VP_);
    float4 a  = *(const float4*)(at + k * 36);   // half-wave broadcast
    acc[0].x = fmaf(a.x, wv.x, acc[0].x); acc[0].y = fmaf(a.x, wv.y, acc[0].y);
    acc[0].z = fmaf(a.x, wv.z, acc[0].z); acc[0].w = fmaf(a.x, wv.w, acc[0].w);
    acc[1].x = fmaf(a.y, wv.x, acc[1].x); acc[1].y = fmaf(a.y, wv.y, acc[1].y);
    acc[1].z = fmaf(a.y, wv.z, acc[1].z); acc[1].w = fmaf(a.y, wv.w, acc[1].w);
    acc[2].x = fmaf(a.z, wv.x, acc[2].x); acc[2].y = fmaf(a.z, wv.y, acc[2].y);
    acc[2].z = fmaf(a.z, wv.z, acc[2].z); acc[2].w = fmaf(a.z, wv.w, acc[2].w);
    acc[3].x = fmaf(a.w, wv.x, acc[3].x); acc[3].y = fmaf(a.w, wv.y, acc[3].y);
    acc[3].z = fmaf(a.w, wv.z, acc[3].z); acc[3].w = fmaf(a.w, wv.w, acc[3].w);
  }

  float bias4[4];
#pragma unroll
  for (int u = 0; u < 4; ++u) bias4[u] = (j + u < V_) ? ob[j + u] : 0.0f;
  const bool tile_full = (n0 + 128 <= V_);   // only blockIdx.x==63 is partial
#pragma unroll
  for (int rr = 0; rr < 4; ++rr) {
    const int b = m0 + ro * 4 + rr;
    float v[4] = {acc[rr].x + bias4[0], acc[rr].y + bias4[1],
                  acc[rr].z + bias4[2], acc[rr].w + bias4[3]};
    float* orow = out + ((size_t)b * T_ + t) * V_ + j;
    if (tile_full) {
      orow[0] = v[0]; orow[1] = v[1]; orow[2] = v[2]; orow[3] = v[3];
    } else {
#pragma unroll
      for (int u = 0; u < 4; ++u)
        if (j + u < V_) orow[u] = v[u];
    }
    float bv = -INFINITY; int bi = 0;
#pragma unroll
    for (int u = 0; u < 4; ++u)
      if (j + u < V_ && v[u] > bv) { bv = v[u]; bi = j + u; }
    // reduce across the 32 col-lanes of this half-wave (rows never cross)
#pragma unroll
    for (int off = 1; off < 32; off <<= 1) {
      float ov = __shfl_xor(bv, off, 64);
      int   oi = __shfl_xor(bi, off, 64);
      if (ov > bv || (ov == bv && oi < bi)) { bv = ov; bi = oi; }
    }
    if ((tid & 31) == 0) {
      pmax[(size_t)b * NTL + blockIdx.x] = bv;
      pidx[(size_t)b * NTL + blockIdx.x] = bi;
    }
  }
}

// ---------------------------------------------------------------------------
// latent: mu/sigma/z from h_enc, then h0 = c0 = z @ init_w + init_b
// (round-0 proven) grid B/4 blocks x 64 threads.
// ---------------------------------------------------------------------------
__global__ __launch_bounds__(64) void latent_k(const float* __restrict__ h,
                                               const float* __restrict__ eps,
                                               const float* __restrict__ mu_w,
                                               const float* __restrict__ mu_b,
                                               const float* __restrict__ sig_w,
                                               const float* __restrict__ sig_b,
                                               const float* __restrict__ iw,
                                               const float* __restrict__ ib,
                                               float* __restrict__ h0,
                                               float* __restrict__ c0) {
  __shared__ float zs[4 * Z_];
  const int tid = threadIdx.x;
  const int m0 = blockIdx.x * 4;
  if (tid < 4 * Z_) {
    int row = tid / Z_, qz = tid - row * Z_;
    const float* hr = h + (size_t)(m0 + row) * H_;
    float mu = mu_b[qz], sg = sig_b[qz];
    for (int k = 0; k < H_; ++k) {
      float hv = hr[k];
      mu = fmaf(hv, mu_w[k * Z_ + qz], mu);
      sg = fmaf(hv, sig_w[k * Z_ + qz], sg);
    }
    zs[tid] = mu + eps[qz] * sg;
  }
  __syncthreads();
  for (int i = tid; i < 4 * H_; i += 64) {
    int row = i / H_, col = i - row * H_;
    float acc = ib[col];
#pragma unroll
    for (int qz = 0; qz < Z_; ++qz)
      acc = fmaf(zs[row * Z_ + qz], iw[qz * H_ + col], acc);
    h0[(size_t)(m0 + row) * H_ + col] = acc;
    c0[(size_t)(m0 + row) * H_ + col] = acc;
  }
}

// ---------------------------------------------------------------------------
extern "C" void kernel_launch(void* const* d_in, const int* in_sizes, int n_in,
                              void* d_out, int out_size, void* d_ws, size_t ws_size,
                              hipStream_t stream) {
  const int*   inputs = (const int*)  d_in[0];
  const float* eps    = (const float*)d_in[1];
  const float* emb    = (const float*)d_in[2];
  const float* inf_k  = (const float*)d_in[3];
  const float* inf_rk = (const float*)d_in[4];
  const float* inf_b  = (const float*)d_in[5];
  const float* mu_w   = (const float*)d_in[6];
  const float* mu_b   = (const float*)d_in[7];
  const float* sig_w  = (const float*)d_in[8];
  const float* sig_b  = (const float*)d_in[9];
  const float* init_w = (const float*)d_in[10];
  const float* init_b = (const float*)d_in[11];
  const float* gen_k  = (const float*)d_in[12];
  const float* gen_rk = (const float*)d_in[13];
  const float* gen_b  = (const float*)d_in[14];
  const float* out_w  = (const float*)d_in[15];
  const float* out_b  = (const float*)d_in[16];
  float* out = (float*)d_out;

  const int B = in_sizes[0] / T_;        // 256
  const int BH = B * H_;

  float* ws = (float*)d_ws;
  size_t off = 0;
  float* EK = ws + off; off += (size_t)V_ * FH_;        // emb @ gen_k
  float* XK = ws + off; off += (size_t)T_ * B * FH_;    // gathered emb @ inf_k
  float* WP = ws + off; off += (size_t)H_ * VP_;        // padded out_w
  float* rkT = ws + off; off += (size_t)2 * FH_ * RKS;  // rkT[inf|gen][764][192]
  float* hbase = ws + off; off += (size_t)8 * BH;       // he0 ce0 he1 ce1 hd0 cd0 hd1 cd1
  float* he[2] = {hbase + 0 * BH, hbase + 2 * BH};
  float* ce[2] = {hbase + 1 * BH, hbase + 3 * BH};
  float* hd[2] = {hbase + 4 * BH, hbase + 6 * BH};
  float* cd[2] = {hbase + 5 * BH, hbase + 7 * BH};
  float* pmax = ws + off; off += (size_t)B * NTL;
  int*   pidx = (int*)(ws + off); off += (size_t)B * NTL;
  float* rkT_inf = rkT;
  float* rkT_gen = rkT + (size_t)FH_ * RKS;

  // zero initial encoder state (he[0], ce[0] are contiguous)
  hipMemsetAsync(hbase, 0, (size_t)2 * BH * sizeof(float), stream);

  // one-time parallel precomputes
  pad_w_kernel<<<(H_ * VP_ + 255) / 256, 256, 0, stream>>>(out_w, WP);
  transpose_rk<<<(2 * FH_ * RKS + 255) / 256, 256, 0, stream>>>(inf_rk, gen_rk, rkT);
  gemm_ew<<<dim3(3, (V_ + 15) / 16), 256, 0, stream>>>(emb, gen_k, EK, V_, nullptr, 0, B);
  gemm_ew<<<dim3(3, (T_ * B) / 16), 256, 0, stream>>>(emb, inf_k, XK, T_ * B, inputs, 1, B);

  // encoder
  for (int t = 0; t < T_; ++t) {
    lstm_step<<<dim3(24, B / 16), 256, 0, stream>>>(
        XK + (size_t)t * B * FH_, rkT_inf, inf_b,
        he[t & 1], ce[t & 1], he[(t + 1) & 1], ce[(t + 1) & 1],
        nullptr, nullptr, 0, 0);
  }

  // latent -> decoder initial state (h = c = init_state)
  latent_k<<<B / 4, 64, 0, stream>>>(he[T_ & 1], eps, mu_w, mu_b, sig_w, sig_b,
                                     init_w, init_b, hd[0], cd[0]);

  // autoregressive decoder
  for (int t = 0; t < T_; ++t) {
    lstm_step<<<dim3(24, B / 16), 256, 0, stream>>>(
        EK, rkT_gen, gen_b,
        hd[t & 1], cd[t & 1], hd[(t + 1) & 1], cd[(t + 1) & 1],
        pmax, pidx, 1, (t == 0) ? 1 : 0);
    logits_argmax<<<dim3(NTL, B / 32), 256, 0, stream>>>(
        hd[(t + 1) & 1], WP, out_b, out, t, pmax, pidx);
  }
}